// Round 3
// baseline (887.846 us; speedup 1.0000x reference)
//
#include <hip/hip_runtime.h>
#include <hip/hip_bf16.h>
#include <math.h>

#define NN 50000
#define NE 800000
#define FIN 256
#define FOUT 32
#define NH 8
#define FE 5
#define AROW 69          // 2*FOUT + FE
#define BK 16

// ---------------- C[h][k] = sum_j a_e[h][j] * Wew[j][k] ----------------
__global__ void k_cmat(const float* __restrict__ a, const float* __restrict__ Wew,
                       float* __restrict__ C) {
    int t = threadIdx.x;
    if (t < NH * FE) {
        int h = t / FE, k = t % FE;
        float s = 0.f;
        for (int j = 0; j < FE; ++j) s += a[h * AROW + 2 * FOUT + j] * Wew[j * FE + k];
        C[t] = s;
    }
}

// ---------------- GEMM: Wh[n][c] = sum_f x[n][f] * W[h][f][o], c=h*32+o ------
// 64x256 block tile, BK=16, 256 threads, 8 rows x (4+4 cols) per thread.
// Thread cols: {tx*4..+3} and {128+tx*4..+3}  -> conflict-free LDS reads,
// coalesced C stores. Fused s1/s2 epilogue.
__global__ __launch_bounds__(256, 4) void k_gemm(const float* __restrict__ x,
                                                 const float* __restrict__ W,
                                                 const float* __restrict__ a,
                                                 float* __restrict__ Wh,
                                                 float* __restrict__ s1,
                                                 float* __restrict__ s2, int nrows) {
    __shared__ float At[BK * 68];    // [k][r], stride 68 (16B-aligned rows)
    __shared__ float Bt[BK * 256];   // [k][c]
    int t = threadIdx.x;
    int ty = t >> 5, tx = t & 31;
    int row0 = blockIdx.x * 64;
    float acc0[8][4], acc1[8][4];
#pragma unroll
    for (int i = 0; i < 8; ++i)
#pragma unroll
        for (int j = 0; j < 4; ++j) { acc0[i][j] = 0.f; acc1[i][j] = 0.f; }

    for (int k0 = 0; k0 < FIN; k0 += BK) {
        // stage A: 64 rows x 16 k, transposed to At[k][r]
        {
            int r = t >> 2, kq = t & 3;     // 64 rows x 4 k-quads
            float4 v = make_float4(0.f, 0.f, 0.f, 0.f);
            int row = row0 + r;
            if (row < nrows) v = *(const float4*)&x[(size_t)row * FIN + k0 + kq * 4];
            At[(kq * 4 + 0) * 68 + r] = v.x;
            At[(kq * 4 + 1) * 68 + r] = v.y;
            At[(kq * 4 + 2) * 68 + r] = v.z;
            At[(kq * 4 + 3) * 68 + r] = v.w;
        }
        // stage B: 16 k x 256 c, transposing W[h][f][o] on the fly
#pragma unroll
        for (int ii = 0; ii < 4; ++ii) {
            int idx = t + ii * 256;          // 0..1023
            int k = idx >> 6, c4 = idx & 63; // col = c4*4
            int h = c4 >> 3, o = (c4 * 4) & 31;
            *(float4*)&Bt[k * 256 + c4 * 4] =
                *(const float4*)&W[(size_t)h * (FIN * FOUT) + (size_t)(k0 + k) * FOUT + o];
        }
        __syncthreads();
#pragma unroll
        for (int k = 0; k < BK; ++k) {
            float4 a0 = *(const float4*)&At[k * 68 + ty * 8];
            float4 a1 = *(const float4*)&At[k * 68 + ty * 8 + 4];
            float4 b0 = *(const float4*)&Bt[k * 256 + tx * 4];
            float4 b1 = *(const float4*)&Bt[k * 256 + 128 + tx * 4];
            float av[8] = {a0.x, a0.y, a0.z, a0.w, a1.x, a1.y, a1.z, a1.w};
            float b0v[4] = {b0.x, b0.y, b0.z, b0.w};
            float b1v[4] = {b1.x, b1.y, b1.z, b1.w};
#pragma unroll
            for (int i = 0; i < 8; ++i)
#pragma unroll
                for (int j = 0; j < 4; ++j) {
                    acc0[i][j] += av[i] * b0v[j];
                    acc1[i][j] += av[i] * b1v[j];
                }
        }
        __syncthreads();
    }
    // write Wh (coalesced float4 x2 per row)
#pragma unroll
    for (int i = 0; i < 8; ++i) {
        int row = row0 + ty * 8 + i;
        if (row < nrows) {
            *(float4*)&Wh[(size_t)row * 256 + tx * 4] =
                make_float4(acc0[i][0], acc0[i][1], acc0[i][2], acc0[i][3]);
            *(float4*)&Wh[(size_t)row * 256 + 128 + tx * 4] =
                make_float4(acc1[i][0], acc1[i][1], acc1[i][2], acc1[i][3]);
        }
    }
    // fused s1/s2: acc0 -> head h0 = tx>>3, acc1 -> head h1 = 4+(tx>>3),
    // this thread's cols within head: o = (tx&7)*4 + j
    int h0 = tx >> 3, h1 = 4 + h0;
    int ob = (tx & 7) * 4;
    float as0[4], ad0[4], as1[4], ad1[4];
#pragma unroll
    for (int j = 0; j < 4; ++j) {
        as0[j] = a[h0 * AROW + ob + j];
        ad0[j] = a[h0 * AROW + FOUT + ob + j];
        as1[j] = a[h1 * AROW + ob + j];
        ad1[j] = a[h1 * AROW + FOUT + ob + j];
    }
#pragma unroll
    for (int i = 0; i < 8; ++i) {
        float p10 = 0.f, p20 = 0.f, p11 = 0.f, p21 = 0.f;
#pragma unroll
        for (int j = 0; j < 4; ++j) {
            p10 += acc0[i][j] * as0[j];
            p20 += acc0[i][j] * ad0[j];
            p11 += acc1[i][j] * as1[j];
            p21 += acc1[i][j] * ad1[j];
        }
#pragma unroll
        for (int d = 1; d < 8; d <<= 1) {
            p10 += __shfl_xor(p10, d);
            p20 += __shfl_xor(p20, d);
            p11 += __shfl_xor(p11, d);
            p21 += __shfl_xor(p21, d);
        }
        int row = row0 + ty * 8 + i;
        if ((tx & 7) == 0 && row < nrows) {
            s1[row * NH + h0] = p10;
            s2[row * NH + h0] = p20;
            s1[row * NH + h1] = p11;
            s2[row * NH + h1] = p21;
        }
    }
}

// ---------------- counts ----------------
__global__ __launch_bounds__(256) void k_count(const int* __restrict__ ei,
                                               int* __restrict__ counts) {
    int e = blockIdx.x * 256 + threadIdx.x;
    if (e < NE) atomicAdd(&counts[ei[e]], 1);
}

// ---------------- scan (3-level) ----------------
__global__ __launch_bounds__(256) void k_scanA(const int* __restrict__ counts,
                                               int* __restrict__ part,
                                               int* __restrict__ bsums, int n) {
    __shared__ int lds[256];
    int t = threadIdx.x;
    int base = blockIdx.x * 1024;
    int i0 = base + t * 4;
    int v0 = (i0 + 0 < n) ? counts[i0 + 0] : 0;
    int v1 = (i0 + 1 < n) ? counts[i0 + 1] : 0;
    int v2 = (i0 + 2 < n) ? counts[i0 + 2] : 0;
    int v3 = (i0 + 3 < n) ? counts[i0 + 3] : 0;
    int l0 = v0, l1 = l0 + v1, l2 = l1 + v2, l3 = l2 + v3;
    lds[t] = l3;
    __syncthreads();
    for (int off = 1; off < 256; off <<= 1) {
        int val = lds[t];
        if (t >= off) val += lds[t - off];
        __syncthreads();
        lds[t] = val;
        __syncthreads();
    }
    int excl = (t == 0) ? 0 : lds[t - 1];
    if (i0 + 0 < n) part[i0 + 0] = excl;
    if (i0 + 1 < n) part[i0 + 1] = excl + l0;
    if (i0 + 2 < n) part[i0 + 2] = excl + l1;
    if (i0 + 3 < n) part[i0 + 3] = excl + l2;
    if (t == 255) bsums[blockIdx.x] = lds[255];
}

__global__ void k_scanB(const int* __restrict__ bsums, int* __restrict__ boffs, int nb) {
    if (threadIdx.x == 0) {
        int run = 0;
        for (int b = 0; b < nb; ++b) { boffs[b] = run; run += bsums[b]; }
    }
}

__global__ __launch_bounds__(256) void k_scanC(int* __restrict__ row_ptr,
                                               const int* __restrict__ boffs, int n, int total) {
    int i = blockIdx.x * 256 + threadIdx.x;
    if (i < n) row_ptr[i] += boffs[i >> 10];
    else if (i == n) row_ptr[n] = total;
}

// ------- scatter + logits: compute e[h], write permuted; no fp atomics -------
__global__ __launch_bounds__(256) void k_scatlog(const int* __restrict__ ei,
                                                 const float* __restrict__ eattr,
                                                 const int* __restrict__ degs,
                                                 const float* __restrict__ s1,
                                                 const float* __restrict__ s2,
                                                 const float* __restrict__ C,
                                                 const int* __restrict__ row_ptr,
                                                 int* __restrict__ fill,
                                                 float* __restrict__ e_perm,
                                                 int2* __restrict__ de_perm) {
    __shared__ float Cl[NH * FE];
    int t = threadIdx.x;
    if (t < NH * FE) Cl[t] = C[t];
    __syncthreads();
    int e = blockIdx.x * 256 + t;
    if (e >= NE) return;
    int src = ei[e], dst = ei[NE + e];
    int dg = degs[e];
    float scale = rsqrtf((float)(dg > 1 ? dg : 1));
    float ea0 = eattr[(size_t)e * FE + 0];
    float ea1 = eattr[(size_t)e * FE + 1];
    float ea2 = eattr[(size_t)e * FE + 2];
    float ea3 = eattr[(size_t)e * FE + 3];
    float ea4 = eattr[(size_t)e * FE + 4];
    float4 s1a = *(const float4*)&s1[src * NH];
    float4 s1b = *(const float4*)&s1[src * NH + 4];
    float4 s2a = *(const float4*)&s2[dst * NH];
    float4 s2b = *(const float4*)&s2[dst * NH + 4];
    float vs1[8] = {s1a.x, s1a.y, s1a.z, s1a.w, s1b.x, s1b.y, s1b.z, s1b.w};
    float vs2[8] = {s2a.x, s2a.y, s2a.z, s2a.w, s2b.x, s2b.y, s2b.z, s2b.w};
    float v[8];
#pragma unroll
    for (int h = 0; h < NH; ++h) {
        float q = vs1[h] + vs2[h] + ea0 * Cl[h * FE + 0] + ea1 * Cl[h * FE + 1] +
                  ea2 * Cl[h * FE + 2] + ea3 * Cl[h * FE + 3] + ea4 * Cl[h * FE + 4];
        q = q > 0.f ? q : 0.2f * q;
        v[h] = q * scale;
    }
    int p = row_ptr[src] + atomicAdd(&fill[src], 1);
    *(float4*)&e_perm[(size_t)p * 8]     = make_float4(v[0], v[1], v[2], v[3]);
    *(float4*)&e_perm[(size_t)p * 8 + 4] = make_float4(v[4], v[5], v[6], v[7]);
    de_perm[p] = make_int2(dst, e);
}

// ------- per-node softmax: one wave per node, shuffle reductions -------
__global__ __launch_bounds__(256) void k_softmax(const int* __restrict__ row_ptr,
                                                 const float* __restrict__ e_perm,
                                                 const int2* __restrict__ de_perm,
                                                 float* __restrict__ alpha_perm,
                                                 float* __restrict__ out_alpha) {
    int t = threadIdx.x;
    int n = blockIdx.x * 4 + (t >> 6);
    if (n >= NN) return;
    int l = t & 63;
    int j = l >> 3, h = l & 7;
    int start = row_ptr[n], deg = row_ptr[n + 1] - start;
    if (deg == 0) return;
    // pass 1: max (clamped at 0)
    float m = 0.f;
    for (int base = 0; base < deg; base += 8) {
        int idx = base + j;
        if (idx < deg) m = fmaxf(m, e_perm[(size_t)(start + idx) * 8 + h]);
    }
    m = fmaxf(m, __shfl_xor(m, 8));
    m = fmaxf(m, __shfl_xor(m, 16));
    m = fmaxf(m, __shfl_xor(m, 32));
    // pass 2: sum of exp
    float s = 0.f;
    for (int base = 0; base < deg; base += 8) {
        int idx = base + j;
        if (idx < deg) s += __expf(e_perm[(size_t)(start + idx) * 8 + h] - m);
    }
    s += __shfl_xor(s, 8);
    s += __shfl_xor(s, 16);
    s += __shfl_xor(s, 32);
    float inv = 1.f / (s + 1e-16f);
    // pass 3: alpha
    for (int base = 0; base < deg; base += 8) {
        int idx = base + j;
        if (idx < deg) {
            size_t p = (size_t)(start + idx);
            float al = __expf(e_perm[p * 8 + h] - m) * inv;
            alpha_perm[p * 8 + h] = al;
            int eid = de_perm[p].y;
            out_alpha[(size_t)eid * 8 + h] = al;
        }
    }
}

// ---------------- message aggregation + ELU, one block per node ----------------
__global__ __launch_bounds__(256) void k_msg(const int* __restrict__ row_ptr,
                                             const int2* __restrict__ de_perm,
                                             const float* __restrict__ alpha_perm,
                                             const float* __restrict__ Wh,
                                             float* __restrict__ out) {
    __shared__ int dl[32];
    __shared__ float al[256];
    int n = blockIdx.x;
    int t = threadIdx.x;
    int h = t >> 5;
    int start = row_ptr[n], end = row_ptr[n + 1];
    float acc = 0.f;
    for (int base = start; base < end; base += 32) {
        int cnt = end - base;
        if (cnt > 32) cnt = 32;
        if (t < cnt) dl[t] = de_perm[base + t].x;
        if (t < cnt * 8) al[t] = alpha_perm[(size_t)base * 8 + t];
        __syncthreads();
        for (int jj = 0; jj < cnt; ++jj) {
            acc += al[jj * 8 + h] * Wh[(size_t)dl[jj] * 256 + t];
        }
        __syncthreads();
    }
    float o = acc > 0.f ? acc : expm1f(acc);
    out[(size_t)n * 256 + t] = o;
}

extern "C" void kernel_launch(void* const* d_in, const int* in_sizes, int n_in,
                              void* d_out, int out_size, void* d_ws, size_t ws_size,
                              hipStream_t stream) {
    const float* x     = (const float*)d_in[0];
    const int*   ei    = (const int*)d_in[1];     // [2][E]
    const float* eattr = (const float*)d_in[2];   // [E][5]
    const int*   degs  = (const int*)d_in[3];     // [E]
    const float* W     = (const float*)d_in[4];   // [8][256][32]
    const float* a     = (const float*)d_in[5];   // [8][69]
    const float* Wew   = (const float*)d_in[6];   // [5][5]

    float* out       = (float*)d_out;                    // N*256
    float* out_alpha = out + (size_t)NN * 256;           // E*8

    // bump allocator over d_ws
    char* p = (char*)d_ws;
    auto alloc = [&](size_t bytes) -> char* {
        char* r = p;
        p += (bytes + 255) & ~(size_t)255;
        return r;
    };
    float* Wh         = (float*)alloc((size_t)NN * 256 * 4);
    float* s1         = (float*)alloc((size_t)NN * NH * 4);
    float* s2         = (float*)alloc((size_t)NN * NH * 4);
    float* Cm         = (float*)alloc(NH * FE * 4);
    int*   counts     = (int*)alloc((size_t)NN * 4);
    int*   row_ptr    = (int*)alloc((size_t)(NN + 1) * 4);
    int*   fill       = (int*)alloc((size_t)NN * 4);
    int*   bsums      = (int*)alloc(64 * 4);
    int*   boffs      = (int*)alloc(64 * 4);
    float* e_perm     = (float*)alloc((size_t)NE * NH * 4);
    int2*  de_perm    = (int2*)alloc((size_t)NE * 8);
    float* alpha_perm = (float*)alloc((size_t)NE * NH * 4);

    hipMemsetAsync(counts, 0, (size_t)NN * 4, stream);
    hipMemsetAsync(fill, 0, (size_t)NN * 4, stream);

    k_cmat<<<1, 64, 0, stream>>>(a, Wew, Cm);
    k_gemm<<<(NN + 63) / 64, 256, 0, stream>>>(x, W, a, Wh, s1, s2, NN);
    k_count<<<(NE + 255) / 256, 256, 0, stream>>>(ei, counts);
    k_scanA<<<(NN + 1023) / 1024, 256, 0, stream>>>(counts, row_ptr, bsums, NN);
    k_scanB<<<1, 64, 0, stream>>>(bsums, boffs, (NN + 1023) / 1024);
    k_scanC<<<(NN + 1 + 255) / 256, 256, 0, stream>>>(row_ptr, boffs, NN, NE);
    k_scatlog<<<(NE + 255) / 256, 256, 0, stream>>>(ei, eattr, degs, s1, s2, Cm,
                                                    row_ptr, fill, e_perm, de_perm);
    k_softmax<<<(NN + 3) / 4, 256, 0, stream>>>(row_ptr, e_perm, de_perm,
                                                alpha_perm, out_alpha);
    k_msg<<<NN, 256, 0, stream>>>(row_ptr, de_perm, alpha_perm, Wh, out);
}

// Round 4
// 426.464 us; speedup vs baseline: 2.0819x; 2.0819x over previous
//
#include <hip/hip_runtime.h>
#include <hip/hip_bf16.h>
#include <math.h>

#define NN 50000
#define NE 800000
#define FIN 256
#define FOUT 32
#define NH 8
#define FE 5
#define AROW 69          // 2*FOUT + FE
#define BK 16

// ---------------- C[h][k] = sum_j a_e[h][j] * Wew[j][k] ----------------
__global__ void k_cmat(const float* __restrict__ a, const float* __restrict__ Wew,
                       float* __restrict__ C) {
    int t = threadIdx.x;
    if (t < NH * FE) {
        int h = t / FE, k = t % FE;
        float s = 0.f;
        for (int j = 0; j < FE; ++j) s += a[h * AROW + 2 * FOUT + j] * Wew[j * FE + k];
        C[t] = s;
    }
}

// ---------------- GEMM: Wh[n][c] = sum_f x[n][f] * W[h][f][o], c=h*32+o ------
// 64x256 block tile, BK=16, 256 threads, 8 rows x (4+4 cols) per thread.
// Thread cols: {tx*4..+3} and {128+tx*4..+3}  -> conflict-free LDS reads,
// coalesced C stores. Fused s1/s2 epilogue.
// NOTE: no min-waves clamp — forcing 4 waves/EU (<=128 VGPR) spills the
// 64-float accumulator to scratch (r3: FETCH 28MB->808MB, dur 174->640us).
__global__ __launch_bounds__(256) void k_gemm(const float* __restrict__ x,
                                              const float* __restrict__ W,
                                              const float* __restrict__ a,
                                              float* __restrict__ Wh,
                                              float* __restrict__ s1,
                                              float* __restrict__ s2, int nrows) {
    __shared__ float At[BK * 68];    // [k][r], stride 68 (16B-aligned rows)
    __shared__ float Bt[BK * 256];   // [k][c]
    int t = threadIdx.x;
    int ty = t >> 5, tx = t & 31;
    int row0 = blockIdx.x * 64;
    float acc0[8][4], acc1[8][4];
#pragma unroll
    for (int i = 0; i < 8; ++i)
#pragma unroll
        for (int j = 0; j < 4; ++j) { acc0[i][j] = 0.f; acc1[i][j] = 0.f; }

    for (int k0 = 0; k0 < FIN; k0 += BK) {
        // stage A: 64 rows x 16 k, transposed to At[k][r]
        {
            int r = t >> 2, kq = t & 3;     // 64 rows x 4 k-quads
            float4 v = make_float4(0.f, 0.f, 0.f, 0.f);
            int row = row0 + r;
            if (row < nrows) v = *(const float4*)&x[(size_t)row * FIN + k0 + kq * 4];
            At[(kq * 4 + 0) * 68 + r] = v.x;
            At[(kq * 4 + 1) * 68 + r] = v.y;
            At[(kq * 4 + 2) * 68 + r] = v.z;
            At[(kq * 4 + 3) * 68 + r] = v.w;
        }
        // stage B: 16 k x 256 c, transposing W[h][f][o] on the fly
#pragma unroll
        for (int ii = 0; ii < 4; ++ii) {
            int idx = t + ii * 256;          // 0..1023
            int k = idx >> 6, c4 = idx & 63; // col = c4*4
            int h = c4 >> 3, o = (c4 * 4) & 31;
            *(float4*)&Bt[k * 256 + c4 * 4] =
                *(const float4*)&W[(size_t)h * (FIN * FOUT) + (size_t)(k0 + k) * FOUT + o];
        }
        __syncthreads();
#pragma unroll
        for (int k = 0; k < BK; ++k) {
            float4 a0 = *(const float4*)&At[k * 68 + ty * 8];
            float4 a1 = *(const float4*)&At[k * 68 + ty * 8 + 4];
            float4 b0 = *(const float4*)&Bt[k * 256 + tx * 4];
            float4 b1 = *(const float4*)&Bt[k * 256 + 128 + tx * 4];
            float av[8] = {a0.x, a0.y, a0.z, a0.w, a1.x, a1.y, a1.z, a1.w};
            float b0v[4] = {b0.x, b0.y, b0.z, b0.w};
            float b1v[4] = {b1.x, b1.y, b1.z, b1.w};
#pragma unroll
            for (int i = 0; i < 8; ++i)
#pragma unroll
                for (int j = 0; j < 4; ++j) {
                    acc0[i][j] += av[i] * b0v[j];
                    acc1[i][j] += av[i] * b1v[j];
                }
        }
        __syncthreads();
    }
    // write Wh (coalesced float4 x2 per row)
#pragma unroll
    for (int i = 0; i < 8; ++i) {
        int row = row0 + ty * 8 + i;
        if (row < nrows) {
            *(float4*)&Wh[(size_t)row * 256 + tx * 4] =
                make_float4(acc0[i][0], acc0[i][1], acc0[i][2], acc0[i][3]);
            *(float4*)&Wh[(size_t)row * 256 + 128 + tx * 4] =
                make_float4(acc1[i][0], acc1[i][1], acc1[i][2], acc1[i][3]);
        }
    }
    // fused s1/s2: acc0 -> head h0 = tx>>3, acc1 -> head h1 = 4+(tx>>3),
    // this thread's cols within head: o = (tx&7)*4 + j
    int h0 = tx >> 3, h1 = 4 + h0;
    int ob = (tx & 7) * 4;
    float as0[4], ad0[4], as1[4], ad1[4];
#pragma unroll
    for (int j = 0; j < 4; ++j) {
        as0[j] = a[h0 * AROW + ob + j];
        ad0[j] = a[h0 * AROW + FOUT + ob + j];
        as1[j] = a[h1 * AROW + ob + j];
        ad1[j] = a[h1 * AROW + FOUT + ob + j];
    }
#pragma unroll
    for (int i = 0; i < 8; ++i) {
        float p10 = 0.f, p20 = 0.f, p11 = 0.f, p21 = 0.f;
#pragma unroll
        for (int j = 0; j < 4; ++j) {
            p10 += acc0[i][j] * as0[j];
            p20 += acc0[i][j] * ad0[j];
            p11 += acc1[i][j] * as1[j];
            p21 += acc1[i][j] * ad1[j];
        }
#pragma unroll
        for (int d = 1; d < 8; d <<= 1) {
            p10 += __shfl_xor(p10, d);
            p20 += __shfl_xor(p20, d);
            p11 += __shfl_xor(p11, d);
            p21 += __shfl_xor(p21, d);
        }
        int row = row0 + ty * 8 + i;
        if ((tx & 7) == 0 && row < nrows) {
            s1[row * NH + h0] = p10;
            s2[row * NH + h0] = p20;
            s1[row * NH + h1] = p11;
            s2[row * NH + h1] = p21;
        }
    }
}

// ---------------- counts ----------------
__global__ __launch_bounds__(256) void k_count(const int* __restrict__ ei,
                                               int* __restrict__ counts) {
    int e = blockIdx.x * 256 + threadIdx.x;
    if (e < NE) atomicAdd(&counts[ei[e]], 1);
}

// ---------------- scan (3-level) ----------------
__global__ __launch_bounds__(256) void k_scanA(const int* __restrict__ counts,
                                               int* __restrict__ part,
                                               int* __restrict__ bsums, int n) {
    __shared__ int lds[256];
    int t = threadIdx.x;
    int base = blockIdx.x * 1024;
    int i0 = base + t * 4;
    int v0 = (i0 + 0 < n) ? counts[i0 + 0] : 0;
    int v1 = (i0 + 1 < n) ? counts[i0 + 1] : 0;
    int v2 = (i0 + 2 < n) ? counts[i0 + 2] : 0;
    int v3 = (i0 + 3 < n) ? counts[i0 + 3] : 0;
    int l0 = v0, l1 = l0 + v1, l2 = l1 + v2, l3 = l2 + v3;
    lds[t] = l3;
    __syncthreads();
    for (int off = 1; off < 256; off <<= 1) {
        int val = lds[t];
        if (t >= off) val += lds[t - off];
        __syncthreads();
        lds[t] = val;
        __syncthreads();
    }
    int excl = (t == 0) ? 0 : lds[t - 1];
    if (i0 + 0 < n) part[i0 + 0] = excl;
    if (i0 + 1 < n) part[i0 + 1] = excl + l0;
    if (i0 + 2 < n) part[i0 + 2] = excl + l1;
    if (i0 + 3 < n) part[i0 + 3] = excl + l2;
    if (t == 255) bsums[blockIdx.x] = lds[255];
}

__global__ void k_scanB(const int* __restrict__ bsums, int* __restrict__ boffs, int nb) {
    if (threadIdx.x == 0) {
        int run = 0;
        for (int b = 0; b < nb; ++b) { boffs[b] = run; run += bsums[b]; }
    }
}

__global__ __launch_bounds__(256) void k_scanC(int* __restrict__ row_ptr,
                                               const int* __restrict__ boffs, int n, int total) {
    int i = blockIdx.x * 256 + threadIdx.x;
    if (i < n) row_ptr[i] += boffs[i >> 10];
    else if (i == n) row_ptr[n] = total;
}

// ------- scatter + logits: compute e[h], write permuted; no fp atomics -------
__global__ __launch_bounds__(256) void k_scatlog(const int* __restrict__ ei,
                                                 const float* __restrict__ eattr,
                                                 const int* __restrict__ degs,
                                                 const float* __restrict__ s1,
                                                 const float* __restrict__ s2,
                                                 const float* __restrict__ C,
                                                 const int* __restrict__ row_ptr,
                                                 int* __restrict__ fill,
                                                 float* __restrict__ e_perm,
                                                 int2* __restrict__ de_perm) {
    __shared__ float Cl[NH * FE];
    int t = threadIdx.x;
    if (t < NH * FE) Cl[t] = C[t];
    __syncthreads();
    int e = blockIdx.x * 256 + t;
    if (e >= NE) return;
    int src = ei[e], dst = ei[NE + e];
    int dg = degs[e];
    float scale = rsqrtf((float)(dg > 1 ? dg : 1));
    float ea0 = eattr[(size_t)e * FE + 0];
    float ea1 = eattr[(size_t)e * FE + 1];
    float ea2 = eattr[(size_t)e * FE + 2];
    float ea3 = eattr[(size_t)e * FE + 3];
    float ea4 = eattr[(size_t)e * FE + 4];
    float4 s1a = *(const float4*)&s1[src * NH];
    float4 s1b = *(const float4*)&s1[src * NH + 4];
    float4 s2a = *(const float4*)&s2[dst * NH];
    float4 s2b = *(const float4*)&s2[dst * NH + 4];
    float vs1[8] = {s1a.x, s1a.y, s1a.z, s1a.w, s1b.x, s1b.y, s1b.z, s1b.w};
    float vs2[8] = {s2a.x, s2a.y, s2a.z, s2a.w, s2b.x, s2b.y, s2b.z, s2b.w};
    float v[8];
#pragma unroll
    for (int h = 0; h < NH; ++h) {
        float q = vs1[h] + vs2[h] + ea0 * Cl[h * FE + 0] + ea1 * Cl[h * FE + 1] +
                  ea2 * Cl[h * FE + 2] + ea3 * Cl[h * FE + 3] + ea4 * Cl[h * FE + 4];
        q = q > 0.f ? q : 0.2f * q;
        v[h] = q * scale;
    }
    int p = row_ptr[src] + atomicAdd(&fill[src], 1);
    *(float4*)&e_perm[(size_t)p * 8]     = make_float4(v[0], v[1], v[2], v[3]);
    *(float4*)&e_perm[(size_t)p * 8 + 4] = make_float4(v[4], v[5], v[6], v[7]);
    de_perm[p] = make_int2(dst, e);
}

// ------- per-node softmax: one wave per node, shuffle reductions -------
__global__ __launch_bounds__(256) void k_softmax(const int* __restrict__ row_ptr,
                                                 const float* __restrict__ e_perm,
                                                 const int2* __restrict__ de_perm,
                                                 float* __restrict__ alpha_perm,
                                                 float* __restrict__ out_alpha) {
    int t = threadIdx.x;
    int n = blockIdx.x * 4 + (t >> 6);
    if (n >= NN) return;
    int l = t & 63;
    int j = l >> 3, h = l & 7;
    int start = row_ptr[n], deg = row_ptr[n + 1] - start;
    if (deg == 0) return;
    // pass 1: max (clamped at 0)
    float m = 0.f;
    for (int base = 0; base < deg; base += 8) {
        int idx = base + j;
        if (idx < deg) m = fmaxf(m, e_perm[(size_t)(start + idx) * 8 + h]);
    }
    m = fmaxf(m, __shfl_xor(m, 8));
    m = fmaxf(m, __shfl_xor(m, 16));
    m = fmaxf(m, __shfl_xor(m, 32));
    // pass 2: sum of exp
    float s = 0.f;
    for (int base = 0; base < deg; base += 8) {
        int idx = base + j;
        if (idx < deg) s += __expf(e_perm[(size_t)(start + idx) * 8 + h] - m);
    }
    s += __shfl_xor(s, 8);
    s += __shfl_xor(s, 16);
    s += __shfl_xor(s, 32);
    float inv = 1.f / (s + 1e-16f);
    // pass 3: alpha
    for (int base = 0; base < deg; base += 8) {
        int idx = base + j;
        if (idx < deg) {
            size_t p = (size_t)(start + idx);
            float al = __expf(e_perm[p * 8 + h] - m) * inv;
            alpha_perm[p * 8 + h] = al;
            int eid = de_perm[p].y;
            out_alpha[(size_t)eid * 8 + h] = al;
        }
    }
}

// ---------------- message aggregation + ELU, one block per node ----------------
__global__ __launch_bounds__(256) void k_msg(const int* __restrict__ row_ptr,
                                             const int2* __restrict__ de_perm,
                                             const float* __restrict__ alpha_perm,
                                             const float* __restrict__ Wh,
                                             float* __restrict__ out) {
    __shared__ int dl[32];
    __shared__ float al[256];
    int n = blockIdx.x;
    int t = threadIdx.x;
    int h = t >> 5;
    int start = row_ptr[n], end = row_ptr[n + 1];
    float acc = 0.f;
    for (int base = start; base < end; base += 32) {
        int cnt = end - base;
        if (cnt > 32) cnt = 32;
        if (t < cnt) dl[t] = de_perm[base + t].x;
        if (t < cnt * 8) al[t] = alpha_perm[(size_t)base * 8 + t];
        __syncthreads();
        for (int jj = 0; jj < cnt; ++jj) {
            acc += al[jj * 8 + h] * Wh[(size_t)dl[jj] * 256 + t];
        }
        __syncthreads();
    }
    float o = acc > 0.f ? acc : expm1f(acc);
    out[(size_t)n * 256 + t] = o;
}

extern "C" void kernel_launch(void* const* d_in, const int* in_sizes, int n_in,
                              void* d_out, int out_size, void* d_ws, size_t ws_size,
                              hipStream_t stream) {
    const float* x     = (const float*)d_in[0];
    const int*   ei    = (const int*)d_in[1];     // [2][E]
    const float* eattr = (const float*)d_in[2];   // [E][5]
    const int*   degs  = (const int*)d_in[3];     // [E]
    const float* W     = (const float*)d_in[4];   // [8][256][32]
    const float* a     = (const float*)d_in[5];   // [8][69]
    const float* Wew   = (const float*)d_in[6];   // [5][5]

    float* out       = (float*)d_out;                    // N*256
    float* out_alpha = out + (size_t)NN * 256;           // E*8

    // bump allocator over d_ws
    char* p = (char*)d_ws;
    auto alloc = [&](size_t bytes) -> char* {
        char* r = p;
        p += (bytes + 255) & ~(size_t)255;
        return r;
    };
    float* Wh         = (float*)alloc((size_t)NN * 256 * 4);
    float* s1         = (float*)alloc((size_t)NN * NH * 4);
    float* s2         = (float*)alloc((size_t)NN * NH * 4);
    float* Cm         = (float*)alloc(NH * FE * 4);
    int*   counts     = (int*)alloc((size_t)NN * 4);
    int*   row_ptr    = (int*)alloc((size_t)(NN + 1) * 4);
    int*   fill       = (int*)alloc((size_t)NN * 4);
    int*   bsums      = (int*)alloc(64 * 4);
    int*   boffs      = (int*)alloc(64 * 4);
    float* e_perm     = (float*)alloc((size_t)NE * NH * 4);
    int2*  de_perm    = (int2*)alloc((size_t)NE * 8);
    float* alpha_perm = (float*)alloc((size_t)NE * NH * 4);

    hipMemsetAsync(counts, 0, (size_t)NN * 4, stream);
    hipMemsetAsync(fill, 0, (size_t)NN * 4, stream);

    k_cmat<<<1, 64, 0, stream>>>(a, Wew, Cm);
    k_gemm<<<(NN + 63) / 64, 256, 0, stream>>>(x, W, a, Wh, s1, s2, NN);
    k_count<<<(NE + 255) / 256, 256, 0, stream>>>(ei, counts);
    k_scanA<<<(NN + 1023) / 1024, 256, 0, stream>>>(counts, row_ptr, bsums, NN);
    k_scanB<<<1, 64, 0, stream>>>(bsums, boffs, (NN + 1023) / 1024);
    k_scanC<<<(NN + 1 + 255) / 256, 256, 0, stream>>>(row_ptr, boffs, NN, NE);
    k_scatlog<<<(NE + 255) / 256, 256, 0, stream>>>(ei, eattr, degs, s1, s2, Cm,
                                                    row_ptr, fill, e_perm, de_perm);
    k_softmax<<<(NN + 3) / 4, 256, 0, stream>>>(row_ptr, e_perm, de_perm,
                                                alpha_perm, out_alpha);
    k_msg<<<NN, 256, 0, stream>>>(row_ptr, de_perm, alpha_perm, Wh, out);
}

// Round 5
// 298.492 us; speedup vs baseline: 2.9744x; 1.4287x over previous
//
#include <hip/hip_runtime.h>
#include <hip/hip_bf16.h>
#include <math.h>

#define NN 50000
#define NE 800000
#define FIN 256
#define FOUT 32
#define NH 8
#define FE 5
#define AROW 69          // 2*FOUT + FE

typedef float f32x4 __attribute__((ext_vector_type(4)));
typedef short bf16x8 __attribute__((ext_vector_type(8)));

// round-to-nearest-even fp32 -> bf16 bits
static __device__ __forceinline__ unsigned short f2bf(float f) {
    unsigned u = __float_as_uint(f);
    unsigned r = (u + 0x7FFFu + ((u >> 16) & 1u)) >> 16;
    return (unsigned short)r;
}
static __device__ __forceinline__ float bf2f(unsigned short b) {
    return __uint_as_float(((unsigned)b) << 16);
}

// ---------------- C[h][k] = sum_j a_e[h][j] * Wew[j][k] ----------------
__global__ void k_cmat(const float* __restrict__ a, const float* __restrict__ Wew,
                       float* __restrict__ C) {
    int t = threadIdx.x;
    if (t < NH * FE) {
        int h = t / FE, k = t % FE;
        float s = 0.f;
        for (int j = 0; j < FE; ++j) s += a[h * AROW + 2 * FOUT + j] * Wew[j * FE + k];
        C[t] = s;
    }
}

// ------- split W into bf16 hi/lo tables, layout Bt[c][k], c = h*32+o -------
__global__ __launch_bounds__(256) void k_prepB(const float* __restrict__ W,
                                               unsigned short* __restrict__ Bh,
                                               unsigned short* __restrict__ Bl) {
    int c = blockIdx.x;          // 0..255
    int k = threadIdx.x;         // 0..255
    int h = c >> 5, o = c & 31;
    float f = W[(size_t)h * (FIN * FOUT) + (size_t)k * FOUT + o];
    unsigned short hi = f2bf(f);
    unsigned short lo = f2bf(f - bf2f(hi));
    Bh[c * 256 + k] = hi;
    Bl[c * 256 + k] = lo;
}

// ------- MFMA GEMM: Wh[n][c] = sum_k x[n][k]*B[k][c], split-bf16 (3 mfma) ---
// 64-row block tile, 4 waves; wave w owns cols w*64..w*64+63 (4 col-tiles)
// and all 4 row-tiles. A staged in LDS (hi/lo bf16, 112B-padded rows);
// B fragments loaded directly from global (L2-resident 256KB tables).
// Fused s1/s2 epilogue (wave's 64 cols = heads 2w, 2w+1).
__global__ __launch_bounds__(256) void k_gemm_mfma(const float* __restrict__ x,
                                                   const unsigned short* __restrict__ Bh,
                                                   const unsigned short* __restrict__ Bl,
                                                   const float* __restrict__ a,
                                                   float* __restrict__ Wh,
                                                   float* __restrict__ s1,
                                                   float* __restrict__ s2, int nrows) {
    __shared__ __align__(16) unsigned short Ah[64 * 56];  // row stride 56 shorts (112B)
    __shared__ __align__(16) unsigned short Al[64 * 56];
    int t = threadIdx.x;
    int w = t >> 6, l = t & 63;
    int r = l & 15, blk = l >> 4;
    int row0 = blockIdx.x * 64;
    int c0 = w * 64;

    f32x4 acc[4][4];
#pragma unroll
    for (int i = 0; i < 4; ++i)
#pragma unroll
        for (int j = 0; j < 4; ++j) acc[i][j] = (f32x4)(0.f);

    int srow = t >> 2, skq = (t & 3) * 8;      // staging: 8 k-elems per thread
    const size_t xrow = (size_t)(row0 + srow) * FIN;

    for (int k0 = 0; k0 < FIN; k0 += 32) {
        // ---- stage A tile (64 rows x 32 k), convert fp32 -> bf16 hi/lo ----
        {
            float v[8];
            if (row0 + srow < nrows) {
                f32x4 u0 = *(const f32x4*)&x[xrow + k0 + skq];
                f32x4 u1 = *(const f32x4*)&x[xrow + k0 + skq + 4];
                v[0] = u0.x; v[1] = u0.y; v[2] = u0.z; v[3] = u0.w;
                v[4] = u1.x; v[5] = u1.y; v[6] = u1.z; v[7] = u1.w;
            } else {
#pragma unroll
                for (int e = 0; e < 8; ++e) v[e] = 0.f;
            }
            bf16x8 hi, lo;
#pragma unroll
            for (int e = 0; e < 8; ++e) {
                unsigned short hb = f2bf(v[e]);
                hi[e] = (short)hb;
                lo[e] = (short)f2bf(v[e] - bf2f(hb));
            }
            *(bf16x8*)&Ah[srow * 56 + skq] = hi;
            *(bf16x8*)&Al[srow * 56 + skq] = lo;
        }
        __syncthreads();
        // ---- A fragments: lane holds row (rt*16 + r), k = blk*8..+7 ----
        bf16x8 ah[4], alo[4];
#pragma unroll
        for (int rt = 0; rt < 4; ++rt) {
            ah[rt]  = *(const bf16x8*)&Ah[(rt * 16 + r) * 56 + blk * 8];
            alo[rt] = *(const bf16x8*)&Al[(rt * 16 + r) * 56 + blk * 8];
        }
        // ---- B fragments direct from global + 3-term mfma ----
#pragma unroll
        for (int ct = 0; ct < 4; ++ct) {
            int c = c0 + ct * 16 + r;
            bf16x8 bh = *(const bf16x8*)&Bh[c * 256 + k0 + blk * 8];
            bf16x8 bl = *(const bf16x8*)&Bl[c * 256 + k0 + blk * 8];
#pragma unroll
            for (int rt = 0; rt < 4; ++rt) {
                acc[rt][ct] = __builtin_amdgcn_mfma_f32_16x16x32_bf16(ah[rt],  bh, acc[rt][ct], 0, 0, 0);
                acc[rt][ct] = __builtin_amdgcn_mfma_f32_16x16x32_bf16(alo[rt], bh, acc[rt][ct], 0, 0, 0);
                acc[rt][ct] = __builtin_amdgcn_mfma_f32_16x16x32_bf16(ah[rt],  bl, acc[rt][ct], 0, 0, 0);
            }
        }
        __syncthreads();
    }

    // ---- write Wh: C/D layout col=lane&15, row=(lane>>4)*4+reg ----
#pragma unroll
    for (int rt = 0; rt < 4; ++rt) {
#pragma unroll
        for (int reg = 0; reg < 4; ++reg) {
            int row = row0 + rt * 16 + blk * 4 + reg;
            if (row < nrows) {
#pragma unroll
                for (int ct = 0; ct < 4; ++ct) {
                    Wh[(size_t)row * 256 + c0 + ct * 16 + r] = acc[rt][ct][reg];
                }
            }
        }
    }
    // ---- fused s1/s2: wave w covers heads h0=2w (ct 0,1), h1=2w+1 (ct 2,3) --
    int h0 = 2 * w, h1 = 2 * w + 1;
    float as0 = a[h0 * AROW + r],       as0b = a[h0 * AROW + 16 + r];
    float ad0 = a[h0 * AROW + 32 + r],  ad0b = a[h0 * AROW + 48 + r];
    float as1 = a[h1 * AROW + r],       as1b = a[h1 * AROW + 16 + r];
    float ad1 = a[h1 * AROW + 32 + r],  ad1b = a[h1 * AROW + 48 + r];
#pragma unroll
    for (int rt = 0; rt < 4; ++rt) {
#pragma unroll
        for (int reg = 0; reg < 4; ++reg) {
            float p10 = acc[rt][0][reg] * as0 + acc[rt][1][reg] * as0b;
            float p20 = acc[rt][0][reg] * ad0 + acc[rt][1][reg] * ad0b;
            float p11 = acc[rt][2][reg] * as1 + acc[rt][3][reg] * as1b;
            float p21 = acc[rt][2][reg] * ad1 + acc[rt][3][reg] * ad1b;
#pragma unroll
            for (int d = 1; d < 16; d <<= 1) {
                p10 += __shfl_xor(p10, d);
                p20 += __shfl_xor(p20, d);
                p11 += __shfl_xor(p11, d);
                p21 += __shfl_xor(p21, d);
            }
            int row = row0 + rt * 16 + blk * 4 + reg;
            if (r == 0 && row < nrows) {
                s1[row * NH + h0] = p10;
                s2[row * NH + h0] = p20;
                s1[row * NH + h1] = p11;
                s2[row * NH + h1] = p21;
            }
        }
    }
}

// ---------------- counts ----------------
__global__ __launch_bounds__(256) void k_count(const int* __restrict__ ei,
                                               int* __restrict__ counts) {
    int e = blockIdx.x * 256 + threadIdx.x;
    if (e < NE) atomicAdd(&counts[ei[e]], 1);
}

// ---------------- scan (3-level) ----------------
__global__ __launch_bounds__(256) void k_scanA(const int* __restrict__ counts,
                                               int* __restrict__ part,
                                               int* __restrict__ bsums, int n) {
    __shared__ int lds[256];
    int t = threadIdx.x;
    int base = blockIdx.x * 1024;
    int i0 = base + t * 4;
    int v0 = (i0 + 0 < n) ? counts[i0 + 0] : 0;
    int v1 = (i0 + 1 < n) ? counts[i0 + 1] : 0;
    int v2 = (i0 + 2 < n) ? counts[i0 + 2] : 0;
    int v3 = (i0 + 3 < n) ? counts[i0 + 3] : 0;
    int l0 = v0, l1 = l0 + v1, l2 = l1 + v2, l3 = l2 + v3;
    lds[t] = l3;
    __syncthreads();
    for (int off = 1; off < 256; off <<= 1) {
        int val = lds[t];
        if (t >= off) val += lds[t - off];
        __syncthreads();
        lds[t] = val;
        __syncthreads();
    }
    int excl = (t == 0) ? 0 : lds[t - 1];
    if (i0 + 0 < n) part[i0 + 0] = excl;
    if (i0 + 1 < n) part[i0 + 1] = excl + l0;
    if (i0 + 2 < n) part[i0 + 2] = excl + l1;
    if (i0 + 3 < n) part[i0 + 3] = excl + l2;
    if (t == 255) bsums[blockIdx.x] = lds[255];
}

__global__ void k_scanB(const int* __restrict__ bsums, int* __restrict__ boffs, int nb) {
    if (threadIdx.x == 0) {
        int run = 0;
        for (int b = 0; b < nb; ++b) { boffs[b] = run; run += bsums[b]; }
    }
}

__global__ __launch_bounds__(256) void k_scanC(int* __restrict__ row_ptr,
                                               const int* __restrict__ boffs, int n, int total) {
    int i = blockIdx.x * 256 + threadIdx.x;
    if (i < n) row_ptr[i] += boffs[i >> 10];
    else if (i == n) row_ptr[n] = total;
}

// ------- scatter + logits: compute e[h], write permuted; no fp atomics -------
__global__ __launch_bounds__(256) void k_scatlog(const int* __restrict__ ei,
                                                 const float* __restrict__ eattr,
                                                 const int* __restrict__ degs,
                                                 const float* __restrict__ s1,
                                                 const float* __restrict__ s2,
                                                 const float* __restrict__ C,
                                                 const int* __restrict__ row_ptr,
                                                 int* __restrict__ fill,
                                                 float* __restrict__ e_perm,
                                                 int2* __restrict__ de_perm) {
    __shared__ float Cl[NH * FE];
    int t = threadIdx.x;
    if (t < NH * FE) Cl[t] = C[t];
    __syncthreads();
    int e = blockIdx.x * 256 + t;
    if (e >= NE) return;
    int src = ei[e], dst = ei[NE + e];
    int dg = degs[e];
    float scale = rsqrtf((float)(dg > 1 ? dg : 1));
    float ea0 = eattr[(size_t)e * FE + 0];
    float ea1 = eattr[(size_t)e * FE + 1];
    float ea2 = eattr[(size_t)e * FE + 2];
    float ea3 = eattr[(size_t)e * FE + 3];
    float ea4 = eattr[(size_t)e * FE + 4];
    float4 s1a = *(const float4*)&s1[src * NH];
    float4 s1b = *(const float4*)&s1[src * NH + 4];
    float4 s2a = *(const float4*)&s2[dst * NH];
    float4 s2b = *(const float4*)&s2[dst * NH + 4];
    float vs1[8] = {s1a.x, s1a.y, s1a.z, s1a.w, s1b.x, s1b.y, s1b.z, s1b.w};
    float vs2[8] = {s2a.x, s2a.y, s2a.z, s2a.w, s2b.x, s2b.y, s2b.z, s2b.w};
    float v[8];
#pragma unroll
    for (int h = 0; h < NH; ++h) {
        float q = vs1[h] + vs2[h] + ea0 * Cl[h * FE + 0] + ea1 * Cl[h * FE + 1] +
                  ea2 * Cl[h * FE + 2] + ea3 * Cl[h * FE + 3] + ea4 * Cl[h * FE + 4];
        q = q > 0.f ? q : 0.2f * q;
        v[h] = q * scale;
    }
    int p = row_ptr[src] + atomicAdd(&fill[src], 1);
    *(float4*)&e_perm[(size_t)p * 8]     = make_float4(v[0], v[1], v[2], v[3]);
    *(float4*)&e_perm[(size_t)p * 8 + 4] = make_float4(v[4], v[5], v[6], v[7]);
    de_perm[p] = make_int2(dst, e);
}

// ------- fused softmax + message aggregation + ELU, one block per node -------
__global__ __launch_bounds__(256) void k_smmsg(const int* __restrict__ row_ptr,
                                               const float* __restrict__ e_perm,
                                               const int2* __restrict__ de_perm,
                                               const float* __restrict__ Wh,
                                               float* __restrict__ out_alpha,
                                               float* __restrict__ out) {
    __shared__ float m_s[NH], inv_s[NH];
    __shared__ float redv[4][NH];
    __shared__ int dl[32];
    __shared__ float al[256];
    int n = blockIdx.x;
    int t = threadIdx.x;
    int w = t >> 6;
    int start = row_ptr[n], deg = row_ptr[n + 1] - start;
    int j = t >> 3, h = t & 7;   // 32 j-lanes x 8 heads
    // ---- pass 1: max (clamped at 0) ----
    float mx = 0.f;
    for (int b = j; b < deg; b += 32)
        mx = fmaxf(mx, e_perm[(size_t)(start + b) * 8 + h]);
    mx = fmaxf(mx, __shfl_xor(mx, 8));
    mx = fmaxf(mx, __shfl_xor(mx, 16));
    mx = fmaxf(mx, __shfl_xor(mx, 32));
    if ((t & 63) < 8) redv[w][t & 63] = mx;
    __syncthreads();
    if (t < 8) m_s[t] = fmaxf(fmaxf(redv[0][t], redv[1][t]), fmaxf(redv[2][t], redv[3][t]));
    __syncthreads();
    // ---- pass 2: sum of exp ----
    float m = m_s[h];
    float sm = 0.f;
    for (int b = j; b < deg; b += 32)
        sm += __expf(e_perm[(size_t)(start + b) * 8 + h] - m);
    sm += __shfl_xor(sm, 8);
    sm += __shfl_xor(sm, 16);
    sm += __shfl_xor(sm, 32);
    if ((t & 63) < 8) redv[w][t & 63] = sm;
    __syncthreads();
    if (t < 8) inv_s[t] = 1.f / (redv[0][t] + redv[1][t] + redv[2][t] + redv[3][t] + 1e-16f);
    __syncthreads();
    // ---- pass 3: alpha + message aggregation ----
    float accv = 0.f;
    int hh = t >> 5;
    for (int base = 0; base < deg; base += 32) {
        int cnt = deg - base;
        if (cnt > 32) cnt = 32;
        if (t < cnt) dl[t] = de_perm[start + base + t].x;
        if (t < cnt * 8) {
            int jj = t >> 3, hc = t & 7;
            size_t p = (size_t)(start + base + jj);
            float av = __expf(e_perm[p * 8 + hc] - m_s[hc]) * inv_s[hc];
            al[t] = av;
            out_alpha[(size_t)de_perm[p].y * 8 + hc] = av;
        }
        __syncthreads();
        for (int jj = 0; jj < cnt; ++jj)
            accv += al[jj * 8 + hh] * Wh[(size_t)dl[jj] * 256 + t];
        __syncthreads();
    }
    out[(size_t)n * 256 + t] = accv > 0.f ? accv : expm1f(accv);
}

extern "C" void kernel_launch(void* const* d_in, const int* in_sizes, int n_in,
                              void* d_out, int out_size, void* d_ws, size_t ws_size,
                              hipStream_t stream) {
    const float* x     = (const float*)d_in[0];
    const int*   ei    = (const int*)d_in[1];     // [2][E]
    const float* eattr = (const float*)d_in[2];   // [E][5]
    const int*   degs  = (const int*)d_in[3];     // [E]
    const float* W     = (const float*)d_in[4];   // [8][256][32]
    const float* a     = (const float*)d_in[5];   // [8][69]
    const float* Wew   = (const float*)d_in[6];   // [5][5]

    float* out       = (float*)d_out;                    // N*256
    float* out_alpha = out + (size_t)NN * 256;           // E*8

    // bump allocator over d_ws
    char* p = (char*)d_ws;
    auto alloc = [&](size_t bytes) -> char* {
        char* r = p;
        p += (bytes + 255) & ~(size_t)255;
        return r;
    };
    float*          Wh      = (float*)alloc((size_t)NN * 256 * 4);
    float*          s1      = (float*)alloc((size_t)NN * NH * 4);
    float*          s2      = (float*)alloc((size_t)NN * NH * 4);
    float*          Cm      = (float*)alloc(NH * FE * 4);
    unsigned short* Bh      = (unsigned short*)alloc((size_t)256 * 256 * 2);
    unsigned short* Bl      = (unsigned short*)alloc((size_t)256 * 256 * 2);
    int*            counts  = (int*)alloc((size_t)NN * 4);
    int*            row_ptr = (int*)alloc((size_t)(NN + 1) * 4);
    int*            fill    = (int*)alloc((size_t)NN * 4);
    int*            bsums   = (int*)alloc(64 * 4);
    int*            boffs   = (int*)alloc(64 * 4);
    float*          e_perm  = (float*)alloc((size_t)NE * NH * 4);
    int2*           de_perm = (int2*)alloc((size_t)NE * 8);

    hipMemsetAsync(counts, 0, (size_t)NN * 4, stream);
    hipMemsetAsync(fill, 0, (size_t)NN * 4, stream);

    k_cmat<<<1, 64, 0, stream>>>(a, Wew, Cm);
    k_prepB<<<256, 256, 0, stream>>>(W, Bh, Bl);
    k_gemm_mfma<<<(NN + 63) / 64, 256, 0, stream>>>(x, Bh, Bl, a, Wh, s1, s2, NN);
    k_count<<<(NE + 255) / 256, 256, 0, stream>>>(ei, counts);
    k_scanA<<<(NN + 1023) / 1024, 256, 0, stream>>>(counts, row_ptr, bsums, NN);
    k_scanB<<<1, 64, 0, stream>>>(bsums, boffs, (NN + 1023) / 1024);
    k_scanC<<<(NN + 1 + 255) / 256, 256, 0, stream>>>(row_ptr, boffs, NN, NE);
    k_scatlog<<<(NE + 255) / 256, 256, 0, stream>>>(ei, eattr, degs, s1, s2, Cm,
                                                    row_ptr, fill, e_perm, de_perm);
    k_smmsg<<<NN, 256, 0, stream>>>(row_ptr, e_perm, de_perm, Wh, out_alpha, out);
}

// Round 6
// 274.166 us; speedup vs baseline: 3.2383x; 1.0887x over previous
//
#include <hip/hip_runtime.h>
#include <hip/hip_bf16.h>
#include <math.h>

#define NN 50000
#define NE 800000
#define FIN 256
#define FOUT 32
#define NH 8
#define FE 5
#define AROW 69          // 2*FOUT + FE

typedef float f32x4 __attribute__((ext_vector_type(4)));
typedef short bf16x8 __attribute__((ext_vector_type(8)));

// round-to-nearest-even fp32 -> bf16 bits
static __device__ __forceinline__ unsigned short f2bf(float f) {
    unsigned u = __float_as_uint(f);
    unsigned r = (u + 0x7FFFu + ((u >> 16) & 1u)) >> 16;
    return (unsigned short)r;
}
static __device__ __forceinline__ float bf2f(unsigned short b) {
    return __uint_as_float(((unsigned)b) << 16);
}

// ---------------- C[h][k] = sum_j a_e[h][j] * Wew[j][k] ----------------
__global__ void k_cmat(const float* __restrict__ a, const float* __restrict__ Wew,
                       float* __restrict__ C) {
    int t = threadIdx.x;
    if (t < NH * FE) {
        int h = t / FE, k = t % FE;
        float s = 0.f;
        for (int j = 0; j < FE; ++j) s += a[h * AROW + 2 * FOUT + j] * Wew[j * FE + k];
        C[t] = s;
    }
}

// ------- split W into bf16 hi/lo tables, layout Bt[c][k], c = h*32+o -------
__global__ __launch_bounds__(256) void k_prepB(const float* __restrict__ W,
                                               unsigned short* __restrict__ Bh,
                                               unsigned short* __restrict__ Bl) {
    int c = blockIdx.x;          // 0..255
    int k = threadIdx.x;         // 0..255
    int h = c >> 5, o = c & 31;
    float f = W[(size_t)h * (FIN * FOUT) + (size_t)k * FOUT + o];
    unsigned short hi = f2bf(f);
    unsigned short lo = f2bf(f - bf2f(hi));
    Bh[c * 256 + k] = hi;
    Bl[c * 256 + k] = lo;
}

// ------- MFMA GEMM: Wh[n][c] = sum_k x[n][k]*B[k][c], 2-term split-bf16 -----
// Wh = x_hi*B_hi + x_hi*B_lo  (x_lo term dropped: err ~2^-9 rel, below the
// bf16 quantization applied to the Wh store anyway).
// 64-row block tile, 4 waves; wave w owns cols w*64..+63. A(hi) staged in LDS.
// B fragments direct from global (L2-resident). Fused s1/s2 epilogue (fp32 acc).
// Wh is stored BF16 (message-gather table).
__global__ __launch_bounds__(256) void k_gemm_mfma(const float* __restrict__ x,
                                                   const unsigned short* __restrict__ Bh,
                                                   const unsigned short* __restrict__ Bl,
                                                   const float* __restrict__ a,
                                                   unsigned short* __restrict__ Whb,
                                                   float* __restrict__ s1,
                                                   float* __restrict__ s2, int nrows) {
    __shared__ __align__(16) unsigned short Ah[64 * 56];  // row stride 56 shorts (112B)
    int t = threadIdx.x;
    int w = t >> 6, l = t & 63;
    int r = l & 15, blk = l >> 4;
    int row0 = blockIdx.x * 64;
    int c0 = w * 64;

    f32x4 acc[4][4];
#pragma unroll
    for (int i = 0; i < 4; ++i)
#pragma unroll
        for (int j = 0; j < 4; ++j) acc[i][j] = (f32x4)(0.f);

    int srow = t >> 2, skq = (t & 3) * 8;      // staging: 8 k-elems per thread
    const size_t xrow = (size_t)(row0 + srow) * FIN;

    for (int k0 = 0; k0 < FIN; k0 += 32) {
        // ---- stage A tile (64 rows x 32 k), convert fp32 -> bf16 hi ----
        {
            float v[8];
            if (row0 + srow < nrows) {
                f32x4 u0 = *(const f32x4*)&x[xrow + k0 + skq];
                f32x4 u1 = *(const f32x4*)&x[xrow + k0 + skq + 4];
                v[0] = u0.x; v[1] = u0.y; v[2] = u0.z; v[3] = u0.w;
                v[4] = u1.x; v[5] = u1.y; v[6] = u1.z; v[7] = u1.w;
            } else {
#pragma unroll
                for (int e = 0; e < 8; ++e) v[e] = 0.f;
            }
            bf16x8 hi;
#pragma unroll
            for (int e = 0; e < 8; ++e) hi[e] = (short)f2bf(v[e]);
            *(bf16x8*)&Ah[srow * 56 + skq] = hi;
        }
        __syncthreads();
        // ---- A fragments: lane holds row (rt*16 + r), k = blk*8..+7 ----
        bf16x8 ah[4];
#pragma unroll
        for (int rt = 0; rt < 4; ++rt)
            ah[rt] = *(const bf16x8*)&Ah[(rt * 16 + r) * 56 + blk * 8];
        // ---- B fragments direct from global + 2-term mfma ----
#pragma unroll
        for (int ct = 0; ct < 4; ++ct) {
            int c = c0 + ct * 16 + r;
            bf16x8 bh = *(const bf16x8*)&Bh[c * 256 + k0 + blk * 8];
            bf16x8 bl = *(const bf16x8*)&Bl[c * 256 + k0 + blk * 8];
#pragma unroll
            for (int rt = 0; rt < 4; ++rt) {
                acc[rt][ct] = __builtin_amdgcn_mfma_f32_16x16x32_bf16(ah[rt], bh, acc[rt][ct], 0, 0, 0);
                acc[rt][ct] = __builtin_amdgcn_mfma_f32_16x16x32_bf16(ah[rt], bl, acc[rt][ct], 0, 0, 0);
            }
        }
        __syncthreads();
    }

    // ---- write Wh (bf16): C/D layout col=lane&15, row=(lane>>4)*4+reg ----
#pragma unroll
    for (int rt = 0; rt < 4; ++rt) {
#pragma unroll
        for (int reg = 0; reg < 4; ++reg) {
            int row = row0 + rt * 16 + blk * 4 + reg;
            if (row < nrows) {
#pragma unroll
                for (int ct = 0; ct < 4; ++ct)
                    Whb[(size_t)row * 256 + c0 + ct * 16 + r] = f2bf(acc[rt][ct][reg]);
            }
        }
    }
    // ---- fused s1/s2: wave w covers heads h0=2w (ct 0,1), h1=2w+1 (ct 2,3) --
    int h0 = 2 * w, h1 = 2 * w + 1;
    float as0 = a[h0 * AROW + r],       as0b = a[h0 * AROW + 16 + r];
    float ad0 = a[h0 * AROW + 32 + r],  ad0b = a[h0 * AROW + 48 + r];
    float as1 = a[h1 * AROW + r],       as1b = a[h1 * AROW + 16 + r];
    float ad1 = a[h1 * AROW + 32 + r],  ad1b = a[h1 * AROW + 48 + r];
#pragma unroll
    for (int rt = 0; rt < 4; ++rt) {
#pragma unroll
        for (int reg = 0; reg < 4; ++reg) {
            float p10 = acc[rt][0][reg] * as0 + acc[rt][1][reg] * as0b;
            float p20 = acc[rt][0][reg] * ad0 + acc[rt][1][reg] * ad0b;
            float p11 = acc[rt][2][reg] * as1 + acc[rt][3][reg] * as1b;
            float p21 = acc[rt][2][reg] * ad1 + acc[rt][3][reg] * ad1b;
#pragma unroll
            for (int d = 1; d < 16; d <<= 1) {
                p10 += __shfl_xor(p10, d);
                p20 += __shfl_xor(p20, d);
                p11 += __shfl_xor(p11, d);
                p21 += __shfl_xor(p21, d);
            }
            int row = row0 + rt * 16 + blk * 4 + reg;
            if (r == 0 && row < nrows) {
                s1[row * NH + h0] = p10;
                s2[row * NH + h0] = p20;
                s1[row * NH + h1] = p11;
                s2[row * NH + h1] = p21;
            }
        }
    }
}

// ---------------- counts ----------------
__global__ __launch_bounds__(256) void k_count(const int* __restrict__ ei,
                                               int* __restrict__ counts) {
    int e = blockIdx.x * 256 + threadIdx.x;
    if (e < NE) atomicAdd(&counts[ei[e]], 1);
}

// ---------------- scan (3-level) ----------------
__global__ __launch_bounds__(256) void k_scanA(const int* __restrict__ counts,
                                               int* __restrict__ part,
                                               int* __restrict__ bsums, int n) {
    __shared__ int lds[256];
    int t = threadIdx.x;
    int base = blockIdx.x * 1024;
    int i0 = base + t * 4;
    int v0 = (i0 + 0 < n) ? counts[i0 + 0] : 0;
    int v1 = (i0 + 1 < n) ? counts[i0 + 1] : 0;
    int v2 = (i0 + 2 < n) ? counts[i0 + 2] : 0;
    int v3 = (i0 + 3 < n) ? counts[i0 + 3] : 0;
    int l0 = v0, l1 = l0 + v1, l2 = l1 + v2, l3 = l2 + v3;
    lds[t] = l3;
    __syncthreads();
    for (int off = 1; off < 256; off <<= 1) {
        int val = lds[t];
        if (t >= off) val += lds[t - off];
        __syncthreads();
        lds[t] = val;
        __syncthreads();
    }
    int excl = (t == 0) ? 0 : lds[t - 1];
    if (i0 + 0 < n) part[i0 + 0] = excl;
    if (i0 + 1 < n) part[i0 + 1] = excl + l0;
    if (i0 + 2 < n) part[i0 + 2] = excl + l1;
    if (i0 + 3 < n) part[i0 + 3] = excl + l2;
    if (t == 255) bsums[blockIdx.x] = lds[255];
}

__global__ void k_scanB(const int* __restrict__ bsums, int* __restrict__ boffs, int nb) {
    if (threadIdx.x == 0) {
        int run = 0;
        for (int b = 0; b < nb; ++b) { boffs[b] = run; run += bsums[b]; }
    }
}

__global__ __launch_bounds__(256) void k_scanC(int* __restrict__ row_ptr,
                                               const int* __restrict__ boffs, int n, int total) {
    int i = blockIdx.x * 256 + threadIdx.x;
    if (i < n) row_ptr[i] += boffs[i >> 10];
    else if (i == n) row_ptr[n] = total;
}

// ------- scatter + logits: compute e[h], write permuted; no fp atomics -------
__global__ __launch_bounds__(256) void k_scatlog(const int* __restrict__ ei,
                                                 const float* __restrict__ eattr,
                                                 const int* __restrict__ degs,
                                                 const float* __restrict__ s1,
                                                 const float* __restrict__ s2,
                                                 const float* __restrict__ C,
                                                 const int* __restrict__ row_ptr,
                                                 int* __restrict__ fill,
                                                 float* __restrict__ e_perm,
                                                 int2* __restrict__ de_perm) {
    __shared__ float Cl[NH * FE];
    int t = threadIdx.x;
    if (t < NH * FE) Cl[t] = C[t];
    __syncthreads();
    int e = blockIdx.x * 256 + t;
    if (e >= NE) return;
    int src = ei[e], dst = ei[NE + e];
    int dg = degs[e];
    float scale = rsqrtf((float)(dg > 1 ? dg : 1));
    float ea0 = eattr[(size_t)e * FE + 0];
    float ea1 = eattr[(size_t)e * FE + 1];
    float ea2 = eattr[(size_t)e * FE + 2];
    float ea3 = eattr[(size_t)e * FE + 3];
    float ea4 = eattr[(size_t)e * FE + 4];
    float4 s1a = *(const float4*)&s1[src * NH];
    float4 s1b = *(const float4*)&s1[src * NH + 4];
    float4 s2a = *(const float4*)&s2[dst * NH];
    float4 s2b = *(const float4*)&s2[dst * NH + 4];
    float vs1[8] = {s1a.x, s1a.y, s1a.z, s1a.w, s1b.x, s1b.y, s1b.z, s1b.w};
    float vs2[8] = {s2a.x, s2a.y, s2a.z, s2a.w, s2b.x, s2b.y, s2b.z, s2b.w};
    float v[8];
#pragma unroll
    for (int h = 0; h < NH; ++h) {
        float q = vs1[h] + vs2[h] + ea0 * Cl[h * FE + 0] + ea1 * Cl[h * FE + 1] +
                  ea2 * Cl[h * FE + 2] + ea3 * Cl[h * FE + 3] + ea4 * Cl[h * FE + 4];
        q = q > 0.f ? q : 0.2f * q;
        v[h] = q * scale;
    }
    int p = row_ptr[src] + atomicAdd(&fill[src], 1);
    *(float4*)&e_perm[(size_t)p * 8]     = make_float4(v[0], v[1], v[2], v[3]);
    *(float4*)&e_perm[(size_t)p * 8 + 4] = make_float4(v[4], v[5], v[6], v[7]);
    de_perm[p] = make_int2(dst, e);
}

// ------- fused softmax + message aggregation + ELU, one block per node -------
// First 32-edge chunk of logits cached in registers (j,h mapping identical
// across max/sum/alpha passes); deg ~ Poisson(16) so this covers >99.99%.
__global__ __launch_bounds__(256) void k_smmsg(const int* __restrict__ row_ptr,
                                               const float* __restrict__ e_perm,
                                               const int2* __restrict__ de_perm,
                                               const unsigned short* __restrict__ Whb,
                                               float* __restrict__ out_alpha,
                                               float* __restrict__ out) {
    __shared__ float m_s[NH], inv_s[NH];
    __shared__ float redv[4][NH];
    __shared__ int dl[32];
    __shared__ float al[256];
    int n = blockIdx.x;
    int t = threadIdx.x;
    int w = t >> 6;
    int start = row_ptr[n], deg = row_ptr[n + 1] - start;
    int j = t >> 3, h = t & 7;   // 32 j-lanes x 8 heads
    // ---- cached chunk-0 logit ----
    float v0 = (j < deg) ? e_perm[(size_t)(start + j) * 8 + h] : 0.f;
    // ---- pass 1: max (clamped at 0) ----
    float mx = fmaxf(v0, 0.f);
    for (int b = 32 + j; b < deg; b += 32)
        mx = fmaxf(mx, e_perm[(size_t)(start + b) * 8 + h]);
    mx = fmaxf(mx, __shfl_xor(mx, 8));
    mx = fmaxf(mx, __shfl_xor(mx, 16));
    mx = fmaxf(mx, __shfl_xor(mx, 32));
    if ((t & 63) < 8) redv[w][t & 63] = mx;
    __syncthreads();
    if (t < 8) m_s[t] = fmaxf(fmaxf(redv[0][t], redv[1][t]), fmaxf(redv[2][t], redv[3][t]));
    __syncthreads();
    // ---- pass 2: sum of exp (chunk 0 from registers) ----
    float m = m_s[h];
    float ex0 = (j < deg) ? __expf(v0 - m) : 0.f;
    float sm = ex0;
    for (int b = 32 + j; b < deg; b += 32)
        sm += __expf(e_perm[(size_t)(start + b) * 8 + h] - m);
    sm += __shfl_xor(sm, 8);
    sm += __shfl_xor(sm, 16);
    sm += __shfl_xor(sm, 32);
    if ((t & 63) < 8) redv[w][t & 63] = sm;
    __syncthreads();
    if (t < 8) inv_s[t] = 1.f / (redv[0][t] + redv[1][t] + redv[2][t] + redv[3][t] + 1e-16f);
    __syncthreads();
    // ---- pass 3: alpha + message aggregation ----
    float accv = 0.f;
    int hh = t >> 5;
    for (int base = 0; base < deg; base += 32) {
        int cnt = deg - base;
        if (cnt > 32) cnt = 32;
        if (t < cnt) dl[t] = de_perm[start + base + t].x;
        if (t < cnt * 8) {
            size_t p = (size_t)(start + base + j);
            float av;
            if (base == 0) av = ex0 * inv_s[h];
            else           av = __expf(e_perm[p * 8 + h] - m_s[h]) * inv_s[h];
            al[t] = av;
            out_alpha[(size_t)de_perm[p].y * 8 + h] = av;
        }
        __syncthreads();
        for (int jj = 0; jj < cnt; ++jj)
            accv += al[jj * 8 + hh] * bf2f(Whb[(size_t)dl[jj] * 256 + t]);
        __syncthreads();
    }
    out[(size_t)n * 256 + t] = accv > 0.f ? accv : expm1f(accv);
}

extern "C" void kernel_launch(void* const* d_in, const int* in_sizes, int n_in,
                              void* d_out, int out_size, void* d_ws, size_t ws_size,
                              hipStream_t stream) {
    const float* x     = (const float*)d_in[0];
    const int*   ei    = (const int*)d_in[1];     // [2][E]
    const float* eattr = (const float*)d_in[2];   // [E][5]
    const int*   degs  = (const int*)d_in[3];     // [E]
    const float* W     = (const float*)d_in[4];   // [8][256][32]
    const float* a     = (const float*)d_in[5];   // [8][69]
    const float* Wew   = (const float*)d_in[6];   // [5][5]

    float* out       = (float*)d_out;                    // N*256
    float* out_alpha = out + (size_t)NN * 256;           // E*8

    // bump allocator over d_ws
    char* p = (char*)d_ws;
    auto alloc = [&](size_t bytes) -> char* {
        char* r = p;
        p += (bytes + 255) & ~(size_t)255;
        return r;
    };
    unsigned short* Whb     = (unsigned short*)alloc((size_t)NN * 256 * 2);
    float*          s1      = (float*)alloc((size_t)NN * NH * 4);
    float*          s2      = (float*)alloc((size_t)NN * NH * 4);
    float*          Cm      = (float*)alloc(NH * FE * 4);
    unsigned short* Bh      = (unsigned short*)alloc((size_t)256 * 256 * 2);
    unsigned short* Bl      = (unsigned short*)alloc((size_t)256 * 256 * 2);
    int*            counts  = (int*)alloc((size_t)NN * 4);
    int*            row_ptr = (int*)alloc((size_t)(NN + 1) * 4);
    int*            fill    = (int*)alloc((size_t)NN * 4);
    int*            bsums   = (int*)alloc(64 * 4);
    int*            boffs   = (int*)alloc(64 * 4);
    float*          e_perm  = (float*)alloc((size_t)NE * NH * 4);
    int2*           de_perm = (int2*)alloc((size_t)NE * 8);

    hipMemsetAsync(counts, 0, (size_t)NN * 4, stream);
    hipMemsetAsync(fill, 0, (size_t)NN * 4, stream);

    k_cmat<<<1, 64, 0, stream>>>(a, Wew, Cm);
    k_prepB<<<256, 256, 0, stream>>>(W, Bh, Bl);
    k_gemm_mfma<<<(NN + 63) / 64, 256, 0, stream>>>(x, Bh, Bl, a, Whb, s1, s2, NN);
    k_count<<<(NE + 255) / 256, 256, 0, stream>>>(ei, counts);
    k_scanA<<<(NN + 1023) / 1024, 256, 0, stream>>>(counts, row_ptr, bsums, NN);
    k_scanB<<<1, 64, 0, stream>>>(bsums, boffs, (NN + 1023) / 1024);
    k_scanC<<<(NN + 1 + 255) / 256, 256, 0, stream>>>(row_ptr, boffs, NN, NE);
    k_scatlog<<<(NE + 255) / 256, 256, 0, stream>>>(ei, eattr, degs, s1, s2, Cm,
                                                    row_ptr, fill, e_perm, de_perm);
    k_smmsg<<<NN, 256, 0, stream>>>(row_ptr, e_perm, de_perm, Whb, out_alpha, out);
}

// Round 7
// 235.369 us; speedup vs baseline: 3.7721x; 1.1648x over previous
//
#include <hip/hip_runtime.h>
#include <hip/hip_bf16.h>
#include <math.h>

#define NN 50000
#define NE 800000
#define FIN 256
#define FOUT 32
#define NH 8
#define FE 5
#define AROW 69          // 2*FOUT + FE

typedef float f32x4 __attribute__((ext_vector_type(4)));
typedef short bf16x8 __attribute__((ext_vector_type(8)));

// round-to-nearest-even fp32 -> bf16 bits
static __device__ __forceinline__ unsigned short f2bf(float f) {
    unsigned u = __float_as_uint(f);
    unsigned r = (u + 0x7FFFu + ((u >> 16) & 1u)) >> 16;
    return (unsigned short)r;
}
static __device__ __forceinline__ float bf2f(unsigned short b) {
    return __uint_as_float(((unsigned)b) << 16);
}

// ---------------- C[h][k] = sum_j a_e[h][j] * Wew[j][k] ----------------
__global__ void k_cmat(const float* __restrict__ a, const float* __restrict__ Wew,
                       float* __restrict__ C) {
    int t = threadIdx.x;
    if (t < NH * FE) {
        int h = t / FE, k = t % FE;
        float s = 0.f;
        for (int j = 0; j < FE; ++j) s += a[h * AROW + 2 * FOUT + j] * Wew[j * FE + k];
        C[t] = s;
    }
}

// ------- split W into bf16 hi/lo tables, layout Bt[c][k], c = h*32+o -------
__global__ __launch_bounds__(256) void k_prepB(const float* __restrict__ W,
                                               unsigned short* __restrict__ Bh,
                                               unsigned short* __restrict__ Bl) {
    int c = blockIdx.x;          // 0..255
    int k = threadIdx.x;         // 0..255
    int h = c >> 5, o = c & 31;
    float f = W[(size_t)h * (FIN * FOUT) + (size_t)k * FOUT + o];
    unsigned short hi = f2bf(f);
    unsigned short lo = f2bf(f - bf2f(hi));
    Bh[c * 256 + k] = hi;
    Bl[c * 256 + k] = lo;
}

// ------- MFMA GEMM: Wh[n][c] = sum_k x[n][k]*B[k][c], 2-term split-bf16 -----
__global__ __launch_bounds__(256) void k_gemm_mfma(const float* __restrict__ x,
                                                   const unsigned short* __restrict__ Bh,
                                                   const unsigned short* __restrict__ Bl,
                                                   const float* __restrict__ a,
                                                   unsigned short* __restrict__ Whb,
                                                   float* __restrict__ s1,
                                                   float* __restrict__ s2, int nrows) {
    __shared__ __align__(16) unsigned short Ah[64 * 56];  // row stride 56 shorts (112B)
    int t = threadIdx.x;
    int w = t >> 6, l = t & 63;
    int r = l & 15, blk = l >> 4;
    int row0 = blockIdx.x * 64;
    int c0 = w * 64;

    f32x4 acc[4][4];
#pragma unroll
    for (int i = 0; i < 4; ++i)
#pragma unroll
        for (int j = 0; j < 4; ++j) acc[i][j] = (f32x4)(0.f);

    int srow = t >> 2, skq = (t & 3) * 8;      // staging: 8 k-elems per thread
    const size_t xrow = (size_t)(row0 + srow) * FIN;

    for (int k0 = 0; k0 < FIN; k0 += 32) {
        // ---- stage A tile (64 rows x 32 k), convert fp32 -> bf16 hi ----
        {
            float v[8];
            if (row0 + srow < nrows) {
                f32x4 u0 = *(const f32x4*)&x[xrow + k0 + skq];
                f32x4 u1 = *(const f32x4*)&x[xrow + k0 + skq + 4];
                v[0] = u0.x; v[1] = u0.y; v[2] = u0.z; v[3] = u0.w;
                v[4] = u1.x; v[5] = u1.y; v[6] = u1.z; v[7] = u1.w;
            } else {
#pragma unroll
                for (int e = 0; e < 8; ++e) v[e] = 0.f;
            }
            bf16x8 hi;
#pragma unroll
            for (int e = 0; e < 8; ++e) hi[e] = (short)f2bf(v[e]);
            *(bf16x8*)&Ah[srow * 56 + skq] = hi;
        }
        __syncthreads();
        bf16x8 ah[4];
#pragma unroll
        for (int rt = 0; rt < 4; ++rt)
            ah[rt] = *(const bf16x8*)&Ah[(rt * 16 + r) * 56 + blk * 8];
#pragma unroll
        for (int ct = 0; ct < 4; ++ct) {
            int c = c0 + ct * 16 + r;
            bf16x8 bh = *(const bf16x8*)&Bh[c * 256 + k0 + blk * 8];
            bf16x8 bl = *(const bf16x8*)&Bl[c * 256 + k0 + blk * 8];
#pragma unroll
            for (int rt = 0; rt < 4; ++rt) {
                acc[rt][ct] = __builtin_amdgcn_mfma_f32_16x16x32_bf16(ah[rt], bh, acc[rt][ct], 0, 0, 0);
                acc[rt][ct] = __builtin_amdgcn_mfma_f32_16x16x32_bf16(ah[rt], bl, acc[rt][ct], 0, 0, 0);
            }
        }
        __syncthreads();
    }

    // ---- write Wh (bf16): C/D layout col=lane&15, row=(lane>>4)*4+reg ----
#pragma unroll
    for (int rt = 0; rt < 4; ++rt) {
#pragma unroll
        for (int reg = 0; reg < 4; ++reg) {
            int row = row0 + rt * 16 + blk * 4 + reg;
            if (row < nrows) {
#pragma unroll
                for (int ct = 0; ct < 4; ++ct)
                    Whb[(size_t)row * 256 + c0 + ct * 16 + r] = f2bf(acc[rt][ct][reg]);
            }
        }
    }
    // ---- fused s1/s2 epilogue ----
    int h0 = 2 * w, h1 = 2 * w + 1;
    float as0 = a[h0 * AROW + r],       as0b = a[h0 * AROW + 16 + r];
    float ad0 = a[h0 * AROW + 32 + r],  ad0b = a[h0 * AROW + 48 + r];
    float as1 = a[h1 * AROW + r],       as1b = a[h1 * AROW + 16 + r];
    float ad1 = a[h1 * AROW + 32 + r],  ad1b = a[h1 * AROW + 48 + r];
#pragma unroll
    for (int rt = 0; rt < 4; ++rt) {
#pragma unroll
        for (int reg = 0; reg < 4; ++reg) {
            float p10 = acc[rt][0][reg] * as0 + acc[rt][1][reg] * as0b;
            float p20 = acc[rt][0][reg] * ad0 + acc[rt][1][reg] * ad0b;
            float p11 = acc[rt][2][reg] * as1 + acc[rt][3][reg] * as1b;
            float p21 = acc[rt][2][reg] * ad1 + acc[rt][3][reg] * ad1b;
#pragma unroll
            for (int d = 1; d < 16; d <<= 1) {
                p10 += __shfl_xor(p10, d);
                p20 += __shfl_xor(p20, d);
                p11 += __shfl_xor(p11, d);
                p21 += __shfl_xor(p21, d);
            }
            int row = row0 + rt * 16 + blk * 4 + reg;
            if (r == 0 && row < nrows) {
                s1[row * NH + h0] = p10;
                s2[row * NH + h0] = p20;
                s1[row * NH + h1] = p11;
                s2[row * NH + h1] = p21;
            }
        }
    }
}

// ---------------- counts ----------------
__global__ __launch_bounds__(256) void k_count(const int* __restrict__ ei,
                                               int* __restrict__ counts) {
    int e = blockIdx.x * 256 + threadIdx.x;
    if (e < NE) atomicAdd(&counts[ei[e]], 1);
}

// ---------------- scan (3-level) ----------------
__global__ __launch_bounds__(256) void k_scanA(const int* __restrict__ counts,
                                               int* __restrict__ part,
                                               int* __restrict__ bsums, int n) {
    __shared__ int lds[256];
    int t = threadIdx.x;
    int base = blockIdx.x * 1024;
    int i0 = base + t * 4;
    int v0 = (i0 + 0 < n) ? counts[i0 + 0] : 0;
    int v1 = (i0 + 1 < n) ? counts[i0 + 1] : 0;
    int v2 = (i0 + 2 < n) ? counts[i0 + 2] : 0;
    int v3 = (i0 + 3 < n) ? counts[i0 + 3] : 0;
    int l0 = v0, l1 = l0 + v1, l2 = l1 + v2, l3 = l2 + v3;
    lds[t] = l3;
    __syncthreads();
    for (int off = 1; off < 256; off <<= 1) {
        int val = lds[t];
        if (t >= off) val += lds[t - off];
        __syncthreads();
        lds[t] = val;
        __syncthreads();
    }
    int excl = (t == 0) ? 0 : lds[t - 1];
    if (i0 + 0 < n) part[i0 + 0] = excl;
    if (i0 + 1 < n) part[i0 + 1] = excl + l0;
    if (i0 + 2 < n) part[i0 + 2] = excl + l1;
    if (i0 + 3 < n) part[i0 + 3] = excl + l2;
    if (t == 255) bsums[blockIdx.x] = lds[255];
}

__global__ void k_scanB(const int* __restrict__ bsums, int* __restrict__ boffs, int nb) {
    if (threadIdx.x == 0) {
        int run = 0;
        for (int b = 0; b < nb; ++b) { boffs[b] = run; run += bsums[b]; }
    }
}

__global__ __launch_bounds__(256) void k_scanC(int* __restrict__ row_ptr,
                                               const int* __restrict__ boffs, int n, int total) {
    int i = blockIdx.x * 256 + threadIdx.x;
    if (i < n) row_ptr[i] += boffs[i >> 10];
    else if (i == n) row_ptr[n] = total;
}

// ------- scatter + logits: compute e[h], write permuted; no fp atomics -------
__global__ __launch_bounds__(256) void k_scatlog(const int* __restrict__ ei,
                                                 const float* __restrict__ eattr,
                                                 const int* __restrict__ degs,
                                                 const float* __restrict__ s1,
                                                 const float* __restrict__ s2,
                                                 const float* __restrict__ C,
                                                 const int* __restrict__ row_ptr,
                                                 int* __restrict__ fill,
                                                 float* __restrict__ e_perm,
                                                 int2* __restrict__ de_perm) {
    __shared__ float Cl[NH * FE];
    int t = threadIdx.x;
    if (t < NH * FE) Cl[t] = C[t];
    __syncthreads();
    int e = blockIdx.x * 256 + t;
    if (e >= NE) return;
    int src = ei[e], dst = ei[NE + e];
    int dg = degs[e];
    float scale = rsqrtf((float)(dg > 1 ? dg : 1));
    float ea0 = eattr[(size_t)e * FE + 0];
    float ea1 = eattr[(size_t)e * FE + 1];
    float ea2 = eattr[(size_t)e * FE + 2];
    float ea3 = eattr[(size_t)e * FE + 3];
    float ea4 = eattr[(size_t)e * FE + 4];
    float4 s1a = *(const float4*)&s1[src * NH];
    float4 s1b = *(const float4*)&s1[src * NH + 4];
    float4 s2a = *(const float4*)&s2[dst * NH];
    float4 s2b = *(const float4*)&s2[dst * NH + 4];
    float vs1[8] = {s1a.x, s1a.y, s1a.z, s1a.w, s1b.x, s1b.y, s1b.z, s1b.w};
    float vs2[8] = {s2a.x, s2a.y, s2a.z, s2a.w, s2b.x, s2b.y, s2b.z, s2b.w};
    float v[8];
#pragma unroll
    for (int h = 0; h < NH; ++h) {
        float q = vs1[h] + vs2[h] + ea0 * Cl[h * FE + 0] + ea1 * Cl[h * FE + 1] +
                  ea2 * Cl[h * FE + 2] + ea3 * Cl[h * FE + 3] + ea4 * Cl[h * FE + 4];
        q = q > 0.f ? q : 0.2f * q;
        v[h] = q * scale;
    }
    int p = row_ptr[src] + atomicAdd(&fill[src], 1);
    *(float4*)&e_perm[(size_t)p * 8]     = make_float4(v[0], v[1], v[2], v[3]);
    *(float4*)&e_perm[(size_t)p * 8 + 4] = make_float4(v[4], v[5], v[6], v[7]);
    de_perm[p] = make_int2(dst, e);
}

// ------- fused softmax + message aggregation + ELU: ONE WAVE PER NODE -------
// 4 independent waves/block, no __syncthreads (divergent deg safe).
// Lane l: softmax role (j=l>>3, h=l&7) handles edges j+8q; aggregation role
// owns output cols l*4..l*4+3 (head l>>3) via ushort4 gathers of bf16 Wh.
__global__ __launch_bounds__(256) void k_smmsg(const int* __restrict__ row_ptr,
                                               const float* __restrict__ e_perm,
                                               const int2* __restrict__ de_perm,
                                               const unsigned short* __restrict__ Whb,
                                               float* __restrict__ out_alpha,
                                               float* __restrict__ out) {
    __shared__ float al[4][256];
    __shared__ int dl[4][32];
    __shared__ int el[4][32];
    int t = threadIdx.x;
    int w = t >> 6, l = t & 63;
    int n = blockIdx.x * 4 + w;
    if (n >= NN) return;
    int start = row_ptr[n], deg = row_ptr[n + 1] - start;
    int j = l >> 3, h = l & 7;

    // ---- chunk-0 logit cache: edges j+8q, q=0..3 ----
    float vc[4];
#pragma unroll
    for (int q = 0; q < 4; ++q) {
        int b = j + 8 * q;
        vc[q] = (b < deg) ? e_perm[(size_t)(start + b) * 8 + h] : -1e30f;
    }
    // ---- max (clamped at 0) ----
    float mx = 0.f;
#pragma unroll
    for (int q = 0; q < 4; ++q) mx = fmaxf(mx, vc[q]);
    for (int b = 32 + j; b < deg; b += 8)
        mx = fmaxf(mx, e_perm[(size_t)(start + b) * 8 + h]);
    mx = fmaxf(mx, __shfl_xor(mx, 8));
    mx = fmaxf(mx, __shfl_xor(mx, 16));
    mx = fmaxf(mx, __shfl_xor(mx, 32));
    float m = mx;                      // per-head max, replicated over j-groups
    // ---- sum of exp ----
    float ex[4];
    float sm = 0.f;
#pragma unroll
    for (int q = 0; q < 4; ++q) { ex[q] = __expf(vc[q] - m); sm += ex[q]; }
    for (int b = 32 + j; b < deg; b += 8)
        sm += __expf(e_perm[(size_t)(start + b) * 8 + h] - m);
    sm += __shfl_xor(sm, 8);
    sm += __shfl_xor(sm, 16);
    sm += __shfl_xor(sm, 32);
    float inv = 1.f / (sm + 1e-16f);
    // ---- chunked alpha + aggregation ----
    f32x4 acc = (f32x4)(0.f);
    int hh = l >> 3;                   // aggregation head for cols l*4..+3
    for (int base = 0; base < deg; base += 32) {
        int cnt = deg - base;
        if (cnt > 32) cnt = 32;
        if (l < cnt) {
            int2 de = de_perm[start + base + l];
            dl[w][l] = de.x;
            el[w][l] = de.y;
        }
        asm volatile("s_waitcnt lgkmcnt(0)" ::: "memory");
#pragma unroll
        for (int q = 0; q < 4; ++q) {
            int b = base + j + 8 * q;
            if (b < deg) {
                float av = (base == 0 ? ex[q]
                                      : __expf(e_perm[(size_t)(start + b) * 8 + h] - m)) * inv;
                al[w][(j + 8 * q) * 8 + h] = av;
                out_alpha[(size_t)el[w][j + 8 * q] * 8 + h] = av;
            }
        }
        asm volatile("s_waitcnt lgkmcnt(0)" ::: "memory");
        for (int jj = 0; jj < cnt; ++jj) {
            int d = dl[w][jj];
            float av = al[w][jj * 8 + hh];
            ushort4 u = *(const ushort4*)&Whb[(size_t)d * 256 + l * 4];
            acc.x += av * bf2f(u.x);
            acc.y += av * bf2f(u.y);
            acc.z += av * bf2f(u.z);
            acc.w += av * bf2f(u.w);
        }
        asm volatile("s_waitcnt lgkmcnt(0)" ::: "memory");
    }
    f32x4 o;
    o.x = acc.x > 0.f ? acc.x : expm1f(acc.x);
    o.y = acc.y > 0.f ? acc.y : expm1f(acc.y);
    o.z = acc.z > 0.f ? acc.z : expm1f(acc.z);
    o.w = acc.w > 0.f ? acc.w : expm1f(acc.w);
    *(f32x4*)&out[(size_t)n * 256 + l * 4] = o;
}

extern "C" void kernel_launch(void* const* d_in, const int* in_sizes, int n_in,
                              void* d_out, int out_size, void* d_ws, size_t ws_size,
                              hipStream_t stream) {
    const float* x     = (const float*)d_in[0];
    const int*   ei    = (const int*)d_in[1];     // [2][E]
    const float* eattr = (const float*)d_in[2];   // [E][5]
    const int*   degs  = (const int*)d_in[3];     // [E]
    const float* W     = (const float*)d_in[4];   // [8][256][32]
    const float* a     = (const float*)d_in[5];   // [8][69]
    const float* Wew   = (const float*)d_in[6];   // [5][5]

    float* out       = (float*)d_out;                    // N*256
    float* out_alpha = out + (size_t)NN * 256;           // E*8

    // bump allocator over d_ws
    char* p = (char*)d_ws;
    auto alloc = [&](size_t bytes) -> char* {
        char* r = p;
        p += (bytes + 255) & ~(size_t)255;
        return r;
    };
    unsigned short* Whb     = (unsigned short*)alloc((size_t)NN * 256 * 2);
    float*          s1      = (float*)alloc((size_t)NN * NH * 4);
    float*          s2      = (float*)alloc((size_t)NN * NH * 4);
    float*          Cm      = (float*)alloc(NH * FE * 4);
    unsigned short* Bh      = (unsigned short*)alloc((size_t)256 * 256 * 2);
    unsigned short* Bl      = (unsigned short*)alloc((size_t)256 * 256 * 2);
    int*            counts  = (int*)alloc((size_t)NN * 4);
    int*            row_ptr = (int*)alloc((size_t)(NN + 1) * 4);
    int*            fill    = (int*)alloc((size_t)NN * 4);
    int*            bsums   = (int*)alloc(64 * 4);
    int*            boffs   = (int*)alloc(64 * 4);
    float*          e_perm  = (float*)alloc((size_t)NE * NH * 4);
    int2*           de_perm = (int2*)alloc((size_t)NE * 8);

    hipMemsetAsync(counts, 0, (size_t)NN * 4, stream);
    hipMemsetAsync(fill, 0, (size_t)NN * 4, stream);

    k_cmat<<<1, 64, 0, stream>>>(a, Wew, Cm);
    k_prepB<<<256, 256, 0, stream>>>(W, Bh, Bl);
    k_gemm_mfma<<<(NN + 63) / 64, 256, 0, stream>>>(x, Bh, Bl, a, Whb, s1, s2, NN);
    k_count<<<(NE + 255) / 256, 256, 0, stream>>>(ei, counts);
    k_scanA<<<(NN + 1023) / 1024, 256, 0, stream>>>(counts, row_ptr, bsums, NN);
    k_scanB<<<1, 64, 0, stream>>>(bsums, boffs, (NN + 1023) / 1024);
    k_scanC<<<(NN + 1 + 255) / 256, 256, 0, stream>>>(row_ptr, boffs, NN, NE);
    k_scatlog<<<(NE + 255) / 256, 256, 0, stream>>>(ei, eattr, degs, s1, s2, Cm,
                                                    row_ptr, fill, e_perm, de_perm);
    k_smmsg<<<(NN + 3) / 4, 256, 0, stream>>>(row_ptr, e_perm, de_perm, Whb,
                                              out_alpha, out);
}